// Round 5
// baseline (513.468 us; speedup 1.0000x reference)
//
#include <hip/hip_runtime.h>
#include <math.h>

#define BB 2
#define NN 8192
#define DD 512

static const float INV_SCALE = 0.04419417382415922f; // 1/sqrt(512)

typedef short s16x8 __attribute__((ext_vector_type(8)));
typedef unsigned short u16x8 __attribute__((ext_vector_type(8)));
typedef float f32x4 __attribute__((ext_vector_type(4)));

#define AS1 __attribute__((address_space(1)))
#define AS3 __attribute__((address_space(3)))

__device__ __forceinline__ unsigned short bfbits(__bf16 h) {
    return __builtin_bit_cast(unsigned short, h);
}

__device__ __forceinline__ void gll16(const void* g, void* l) {
    __builtin_amdgcn_global_load_lds((const AS1 unsigned int*)g, (AS3 unsigned int*)l, 16, 0, 0);
}

// ---------------------------------------------------------------------------
// convX: X f32 -> Xhi, Xlo bf16 (hi = rne(x), lo = rne(x - hi))
// ---------------------------------------------------------------------------
__global__ __launch_bounds__(256) void convx_k(
    const float* __restrict__ X, unsigned short* __restrict__ Xhi,
    unsigned short* __restrict__ Xlo)
{
    long i = (long)blockIdx.x * 256 + threadIdx.x;   // float4 index
    float4 x = ((const float4*)X)[i];
    __bf16 h0 = (__bf16)x.x, h1 = (__bf16)x.y, h2 = (__bf16)x.z, h3 = (__bf16)x.w;
    ushort4 hi4 = make_ushort4(bfbits(h0), bfbits(h1), bfbits(h2), bfbits(h3));
    __bf16 l0 = (__bf16)(x.x - (float)h0), l1 = (__bf16)(x.y - (float)h1);
    __bf16 l2 = (__bf16)(x.z - (float)h2), l3 = (__bf16)(x.w - (float)h3);
    ushort4 lo4 = make_ushort4(bfbits(l0), bfbits(l1), bfbits(l2), bfbits(l3));
    ((ushort4*)Xhi)[i] = hi4;
    ((ushort4*)Xlo)[i] = lo4;
}

// ---------------------------------------------------------------------------
// convW: Wqk (512x1024) -> WqkT hi/lo (1024x512 bf16); Wv (512x512) -> WvT hi
// ---------------------------------------------------------------------------
__global__ __launch_bounds__(256) void convw_k(
    const float* __restrict__ Wqk, const float* __restrict__ Wv,
    unsigned short* __restrict__ QTh, unsigned short* __restrict__ QTl,
    unsigned short* __restrict__ VTh, unsigned short* __restrict__ VTl)
{
    int i = blockIdx.x * 256 + threadIdx.x;          // < 786432
    float val; unsigned short *ph, *pl;
    if (i < 524288) {
        int n = i >> 9, k = i & 511;
        val = Wqk[k * 1024 + n]; ph = QTh + i; pl = QTl + i;
    } else {
        int o = i - 524288; int n = o >> 9, k = o & 511;
        val = Wv[k * 512 + n]; ph = VTh + o; pl = VTl + o;
    }
    __bf16 h = (__bf16)val;
    __bf16 l = (__bf16)(val - (float)h);
    *ph = bfbits(h); *pl = bfbits(l);
}

// ---------------------------------------------------------------------------
// qkv MFMA GEMM (round-3/4 structure, BK=32, dbuf, swizzled, __syncthreads).
// EPI 0: fp32 C.  EPI 1: qk split (q fp32 / km fp32 + kmT bf16).
// ---------------------------------------------------------------------------
template <int EPI, int NT>
__global__ __launch_bounds__(256, 2) void mfma_gemm(
    const unsigned short* __restrict__ A0, const unsigned short* __restrict__ A1,
    const unsigned short* __restrict__ B0, const unsigned short* __restrict__ B1,
    float* __restrict__ C,
    float* __restrict__ q, float* __restrict__ km,
    unsigned short* __restrict__ kmT, const float* __restrict__ mask,
    int N, int K)
{
    constexpr int BK = 32;
    constexpr int TILE_SH = 128 * BK;

    __shared__ unsigned short Asm[2 * TILE_SH];
    __shared__ unsigned short Bsm[2 * TILE_SH];

    const int t = threadIdx.x;
    const int wv = t >> 6, lane = t & 63;
    const int wm = wv >> 1, wn = wv & 1;
    const long m0 = blockIdx.x * 128;
    const int n0 = blockIdx.y * 128;

    f32x4 acc[4][4];
#pragma unroll
    for (int i = 0; i < 4; ++i)
#pragma unroll
        for (int j = 0; j < 4; ++j) acc[i][j] = {0.f, 0.f, 0.f, 0.f};

    const int swzcol = ((lane & 3) ^ ((lane >> 2) & 3)) * 16;   // byte offset
    auto stageA16 = [&](int term, int k0, int buf) {
        const unsigned short* Ab = (term < 2) ? A0 : A1;
#pragma unroll
        for (int u = 0; u < 2; ++u) {
            int c = wv * 2 + u;                       // chunk 0..7
            int row = c * 16 + (lane >> 2);
            gll16((const char*)Ab + ((m0 + row) * (long)K + k0) * 2 + swzcol,
                  (char*)Asm + buf * (TILE_SH * 2) + c * 1024);
        }
    };
    auto stageB16 = [&](int term, int k0, int buf) {
        const unsigned short* Bb = (NT == 3 && term == 1) ? B1 : B0;
#pragma unroll
        for (int u = 0; u < 2; ++u) {
            int c = wv * 2 + u;
            int row = c * 16 + (lane >> 2);
            gll16((const char*)Bb + ((long)(n0 + row) * K + k0) * 2 + swzcol,
                  (char*)Bsm + buf * (TILE_SH * 2) + c * 1024);
        }
    };

    stageA16(0, 0, 0);
    stageB16(0, 0, 0);
    __syncthreads();

    const int NTILES = NT * (K / BK);
    int cur = 0, term = 0, k0 = 0;
    const int g = lane >> 4;

#pragma unroll 2
    for (int tt = 0; tt < NTILES; ++tt) {
        int k0n = k0 + BK, termn = term;
        if (k0n == K) { k0n = 0; ++termn; }
        const bool hasNext = (tt + 1 < NTILES);

        if (hasNext) {
            stageA16(termn, k0n, cur ^ 1);
            stageB16(termn, k0n, cur ^ 1);
        }

        s16x8 av[4], bv[4];
#pragma unroll
        for (int f = 0; f < 4; ++f) {
            int ra = wm * 64 + f * 16 + (lane & 15);
            int rb = wn * 64 + f * 16 + (lane & 15);
            av[f] = *(const s16x8*)(Asm + cur * TILE_SH + ra * BK + ((g ^ (ra & 3)) << 3));
            bv[f] = *(const s16x8*)(Bsm + cur * TILE_SH + rb * BK + ((g ^ (rb & 3)) << 3));
        }
#pragma unroll
        for (int fm = 0; fm < 4; ++fm)
#pragma unroll
            for (int fn = 0; fn < 4; ++fn)
                acc[fm][fn] = __builtin_amdgcn_mfma_f32_16x16x32_bf16(
                    av[fm], bv[fn], acc[fm][fn], 0, 0, 0);

        __syncthreads();
        cur ^= 1; term = termn; k0 = k0n;
    }

    const long rbase = m0 + wm * 64;
    const int cbase = n0 + wn * 64;

    if constexpr (EPI == 0) {
#pragma unroll
        for (int fm = 0; fm < 4; ++fm) {
            long rb = rbase + fm * 16 + ((lane >> 4) << 2);
#pragma unroll
            for (int fn = 0; fn < 4; ++fn) {
                int c = cbase + fn * 16 + (lane & 15);
#pragma unroll
                for (int j = 0; j < 4; ++j)
                    C[(rb + j) * (long)N + c] = acc[fm][fn][j];
            }
        }
    } else {
        const bool isq = (n0 < 512);
#pragma unroll
        for (int fm = 0; fm < 4; ++fm) {
            long rb = rbase + fm * 16 + ((lane >> 4) << 2);
#pragma unroll
            for (int fn = 0; fn < 4; ++fn) {
                int c = cbase + fn * 16 + (lane & 15);
                if (isq) {
#pragma unroll
                    for (int j = 0; j < 4; ++j)
                        q[(rb + j) * 512L + c] = acc[fm][fn][j];
                } else {
                    int c2 = c - 512;
                    float kv[4];
#pragma unroll
                    for (int j = 0; j < 4; ++j) {
                        kv[j] = acc[fm][fn][j] * mask[rb + j];
                        km[(rb + j) * 512L + c2] = kv[j];
                    }
                    ushort4 pk = make_ushort4(bfbits((__bf16)kv[0]), bfbits((__bf16)kv[1]),
                                              bfbits((__bf16)kv[2]), bfbits((__bf16)kv[3]));
                    long b = rb >> 13, r = rb & 8191;
                    *(ushort4*)(kmT + (b << 22) + ((long)c2 << 13) + r) = pk;
                }
            }
        }
    }
}

// ---------------------------------------------------------------------------
// Big GEMM: w-partials += rowsum(q .* (adj @ km)).  BM=BN=128, BK=64,
// dbuf LDS (64 KB, 2 blocks/CU), T3/T4 counted-vmcnt pipeline:
//   raw s_barrier, vmcnt(8) at the barrier (A-loads for t+2 stay in flight),
//   A: adj f32 global->reg (ring of 2) -> cvt bf16 -> swizzled ds_write,
//   B: kmT bf16 via global_load_lds with pre-swizzled source (slot ^= row&7).
// Issue order pinned: gll16 B first, then A reg-loads (sched_barrier).
// ---------------------------------------------------------------------------
__global__ __launch_bounds__(256, 2) void adj_gemm(
    const float* __restrict__ adj,          // [B][8192][8192]
    const unsigned short* __restrict__ kmT, // [B][512][8192] bf16 (B^T)
    const float* __restrict__ q,            // [B*8192][512]
    float* __restrict__ w)                  // [B*8192] (atomic accum)
{
    constexpr int BK = 64;
    constexpr int TS = 128 * BK;            // shorts per buffer (8192)
    constexpr int NT = NN / BK;             // 128 K-steps

    __shared__ unsigned short Asm[2 * TS];  // 32 KB
    __shared__ unsigned short Bsm[2 * TS];  // 32 KB

    const int t = threadIdx.x;
    const int wv = t >> 6, lane = t & 63;
    const int wm = wv >> 1, wn = wv & 1;
    const int z = blockIdx.z;
    const long m0 = blockIdx.x * 128;
    const int n0 = blockIdx.y * 128;

    const float* Az = adj + (long)z * NN * NN;
    const unsigned short* Bz = kmT + ((long)z << 22);

    f32x4 acc[4][4];
#pragma unroll
    for (int i = 0; i < 4; ++i)
#pragma unroll
        for (int j = 0; j < 4; ++j) acc[i][j] = {0.f, 0.f, 0.f, 0.f};

    // ---- B staging: 16 chunks of 1KB (8 rows x 128B), 4 per wave ----
    const int bswz = ((lane & 7) ^ (lane >> 3)) << 4;   // pre-swizzled src byte off
    auto stageB = [&](int ttile, int buf) {
        const int k0 = ttile * BK;
#pragma unroll
        for (int u = 0; u < 4; ++u) {
            int c = wv * 4 + u;                  // 0..15
            int row = c * 8 + (lane >> 3);       // 0..127
            gll16((const char*)Bz + ((long)(n0 + row) * NN + k0) * 2 + bswz,
                  (char*)Bsm + buf * (TS * 2) + c * 1024);
        }
    };

    // ---- A staging: 128x64 f32 -> reg (8 float4/thread) -> bf16 ds_write ----
    const int arow = t >> 1;                     // 0..127
    const int asl0 = (t & 1) * 4;                // slot base 0 or 4
    auto issueA = [&](int ttile, float4 (&r)[8]) {
        const float* s = Az + (m0 + arow) * (long)NN + ttile * BK + asl0 * 8;
#pragma unroll
        for (int u = 0; u < 4; ++u) {
            r[2 * u]     = *(const float4*)(s + u * 8);
            r[2 * u + 1] = *(const float4*)(s + u * 8 + 4);
        }
    };
    auto commitA = [&](float4 (&r)[8], int buf) {
#pragma unroll
        for (int u = 0; u < 4; ++u) {
            float4 a = r[2 * u], b = r[2 * u + 1];
            u16x8 pk;
            pk[0] = bfbits((__bf16)a.x); pk[1] = bfbits((__bf16)a.y);
            pk[2] = bfbits((__bf16)a.z); pk[3] = bfbits((__bf16)a.w);
            pk[4] = bfbits((__bf16)b.x); pk[5] = bfbits((__bf16)b.y);
            pk[6] = bfbits((__bf16)b.z); pk[7] = bfbits((__bf16)b.w);
            *(u16x8*)(Asm + buf * TS + arow * 64 + (((asl0 + u) ^ (arow & 7)) << 3)) = pk;
        }
    };

    const int g = lane >> 4;
    auto compute = [&](int buf) {
#pragma unroll
        for (int ks = 0; ks < 2; ++ks) {
            s16x8 av[4], bv[4];
#pragma unroll
            for (int f = 0; f < 4; ++f) {
                int ra = wm * 64 + f * 16 + (lane & 15);
                int rb = wn * 64 + f * 16 + (lane & 15);
                av[f] = *(const s16x8*)(Asm + buf * TS + ra * 64
                         + (((g + ks * 4) ^ (ra & 7)) << 3));
                bv[f] = *(const s16x8*)(Bsm + buf * TS + rb * 64
                         + (((g + ks * 4) ^ (rb & 7)) << 3));
            }
#pragma unroll
            for (int fm = 0; fm < 4; ++fm)
#pragma unroll
                for (int fn = 0; fn < 4; ++fn)
                    acc[fm][fn] = __builtin_amdgcn_mfma_f32_16x16x32_bf16(
                        av[fm], bv[fn], acc[fm][fn], 0, 0, 0);
        }
    };

#define CBAR() do { \
        asm volatile("s_waitcnt vmcnt(8) lgkmcnt(0)" ::: "memory"); \
        __builtin_amdgcn_s_barrier(); \
        asm volatile("" ::: "memory"); \
    } while (0)

    float4 rA0[8], rA1[8];

    // prologue: B(0) gll16 (oldest), A(0), A(1) in regs; commit A(0) -> buf0
    stageB(0, 0);
    __builtin_amdgcn_sched_barrier(0);
    issueA(0, rA0);
    issueA(1, rA1);
    commitA(rA0, 0);           // compiler inserts counted vmcnt for rA0
    CBAR();                    // B(0) complete; A(1) loads remain in flight

    for (int tt = 0; tt < NT; tt += 2) {
        // even iteration: compute buf0, stage into buf1
        if (tt + 1 < NT) stageB(tt + 1, 1);
        __builtin_amdgcn_sched_barrier(0);
        if (tt + 2 < NT) issueA(tt + 2, rA0);
        compute(0);
        if (tt + 1 < NT) commitA(rA1, 1);
        CBAR();
        // odd iteration: compute buf1, stage into buf0
        if (tt + 2 < NT) stageB(tt + 2, 0);
        __builtin_amdgcn_sched_barrier(0);
        if (tt + 3 < NT) issueA(tt + 3, rA1);
        compute(1);
        if (tt + 2 < NT) commitA(rA0, 0);
        CBAR();
    }
#undef CBAR

    // ---- fused epilogue: w[r] += sum_c q[r,c] * C[r,c] ----
    const long zrow = (long)z * NN;
    const long rbase = m0 + wm * 64;
    const int cbase = n0 + wn * 64;
#pragma unroll
    for (int fm = 0; fm < 4; ++fm) {
#pragma unroll
        for (int j = 0; j < 4; ++j) {
            long r = zrow + rbase + fm * 16 + ((lane >> 4) << 2) + j;
            const float* qr = q + r * 512L + cbase + (lane & 15);
            float s = 0.f;
#pragma unroll
            for (int fn = 0; fn < 4; ++fn)
                s += qr[fn * 16] * acc[fm][fn][j];
            s += __shfl_xor(s, 1); s += __shfl_xor(s, 2);
            s += __shfl_xor(s, 4); s += __shfl_xor(s, 8);
            if ((lane & 15) == 0) atomicAdd(w + r, s);
        }
    }
}

// ---------------------------------------------------------------------------
__global__ __launch_bounds__(256) void fixup_k(
    float* __restrict__ w, const float* __restrict__ mask)
{
    int i = blockIdx.x * 256 + threadIdx.x;
    w[i] *= INV_SCALE * mask[i];
}

// ---------------------------------------------------------------------------
// Refinement: exact fp32 recompute of w for rows near the max.
// ---------------------------------------------------------------------------
__global__ __launch_bounds__(256) void wmax_k(const float* __restrict__ w,
                                              float* __restrict__ wmax)
{
    const int b = blockIdx.x;
    const float* wr = w + (long)b * NN;
    const int t = threadIdx.x;
    float m = -3.4e38f;
    for (int i = t; i < NN; i += 256) m = fmaxf(m, wr[i]);
#pragma unroll
    for (int o = 32; o > 0; o >>= 1) m = fmaxf(m, __shfl_down(m, o));
    __shared__ float red[4];
    if ((t & 63) == 0) red[t >> 6] = m;
    __syncthreads();
    if (t == 0) wmax[b] = fmaxf(fmaxf(red[0], red[1]), fmaxf(red[2], red[3]));
}

__global__ __launch_bounds__(256) void select_k(
    const float* __restrict__ w, const float* __restrict__ wmax,
    int* __restrict__ count, int* __restrict__ cand)
{
    int i = blockIdx.x * 256 + threadIdx.x;  // 16384
    int b = i >> 13;
    if (w[i] >= wmax[b] - 15.f) {
        int p = atomicAdd(count, 1);
        if (p < 128) cand[p] = i;
    }
}

__global__ __launch_bounds__(256) void refine_k(
    const float* __restrict__ q, const float* __restrict__ km,
    const float* __restrict__ adj, const int* __restrict__ cand,
    const int* __restrict__ count, float* __restrict__ partial)
{
    int y = blockIdx.y;
    int cnt = *count; if (cnt > 128) cnt = 128;
    if (y >= cnt) return;
    const int row = cand[y];
    const int b = row >> 13, r = row & 8191;
    const int x = blockIdx.x;
    const int t = threadIdx.x, w = t >> 6, l = t & 63;

    const float* qr = q + (long)row * 512 + l * 8;
    const float4 q0 = *(const float4*)qr;
    const float4 q1 = *(const float4*)(qr + 4);
    const float* kmB = km + ((long)b << 13) * 512;
    const float* adjR = adj + (((long)b << 13) + r) * 8192L;

    float acc = 0.f;
    const int jbase = x * 128 + w * 32;
    for (int i = 0; i < 32; ++i) {
        int j = jbase + i;
        const float* kr = kmB + (long)j * 512 + l * 8;
        const float4 k0 = *(const float4*)kr;
        const float4 k1 = *(const float4*)(kr + 4);
        float d = q0.x * k0.x + q0.y * k0.y + q0.z * k0.z + q0.w * k0.w
                + q1.x * k1.x + q1.y * k1.y + q1.z * k1.z + q1.w * k1.w;
#pragma unroll
        for (int o = 32; o > 0; o >>= 1) d += __shfl_down(d, o);
        if (l == 0) acc += adjR[j] * d;
    }
    __shared__ float red[4];
    if (l == 0) red[w] = acc;
    __syncthreads();
    if (t == 0) partial[y * 64 + x] = red[0] + red[1] + red[2] + red[3];
}

__global__ __launch_bounds__(128) void apply_k(
    const int* __restrict__ cand, const int* __restrict__ count,
    const float* __restrict__ partial, const float* __restrict__ mask,
    float* __restrict__ w)
{
    int t = threadIdx.x;
    int cnt = *count; if (cnt > 128) cnt = 128;
    if (t < cnt) {
        float s = 0.f;
        for (int x = 0; x < 64; ++x) s += partial[t * 64 + x];
        int row = cand[t];
        w[row] = s * INV_SCALE * mask[row];
    }
}

// ---------------------------------------------------------------------------
__global__ __launch_bounds__(1024) void softmax_k(
    const float* __restrict__ w, float* __restrict__ p)
{
    const int b = blockIdx.x;
    const float* wr = w + (long)b * NN;
    float* pr = p + (long)b * NN;
    const int t = threadIdx.x;
    __shared__ float red[16];
    __shared__ float bmax, bsum;

    float m = -3.4e38f;
    for (int i = t; i < NN; i += 1024) m = fmaxf(m, wr[i]);
#pragma unroll
    for (int o = 32; o > 0; o >>= 1) m = fmaxf(m, __shfl_down(m, o));
    if ((t & 63) == 0) red[t >> 6] = m;
    __syncthreads();
    if (t == 0) {
        float mm = red[0];
        for (int i = 1; i < 16; ++i) mm = fmaxf(mm, red[i]);
        bmax = mm;
    }
    __syncthreads();
    const float M = bmax;

    float s = 0.f;
    for (int i = t; i < NN; i += 1024) s += expf(wr[i] - M);
#pragma unroll
    for (int o = 32; o > 0; o >>= 1) s += __shfl_down(s, o);
    __syncthreads();
    if ((t & 63) == 0) red[t >> 6] = s;
    __syncthreads();
    if (t == 0) {
        float ss = 0.f;
        for (int i = 0; i < 16; ++i) ss += red[i];
        bsum = ss;
    }
    __syncthreads();
    const float invS = 1.f / bsum;
    for (int i = t; i < NN; i += 1024) pr[i] = expf(wr[i] - M) * invS;
}

__global__ __launch_bounds__(256) void scale_k(
    const float* __restrict__ v, const float* __restrict__ p,
    float* __restrict__ out)
{
    const long i = (long)blockIdx.x * 256 + threadIdx.x;  // float4 index
    const int row = (int)(i >> 7);
    const float pv = p[row];
    float4 vv = ((const float4*)v)[i];
    vv.x *= pv; vv.y *= pv; vv.z *= pv; vv.w *= pv;
    ((float4*)out)[i] = vv;
}

// ---------------------------------------------------------------------------
extern "C" void kernel_launch(void* const* d_in, const int* in_sizes, int n_in,
                              void* d_out, int out_size, void* d_ws, size_t ws_size,
                              hipStream_t stream)
{
    const float* X    = (const float*)d_in[0];
    const float* adj  = (const float*)d_in[1];
    const float* mask = (const float*)d_in[2];
    const float* Wqk  = (const float*)d_in[3];
    const float* Wv   = (const float*)d_in[4];
    float* out = (float*)d_out;

    char* ws = (char*)d_ws;
    const long SZB = 33554432;  // 16384*512*4 bytes
    float* q_buf  = (float*)(ws);
    float* km_buf = (float*)(ws + SZB);
    float* v_buf  = (float*)(ws + 2 * SZB);
    unsigned short* Xhi = (unsigned short*)(ws + 3 * SZB);
    unsigned short* Xlo = Xhi + 8388608;
    unsigned short* kmT = (unsigned short*)(ws + 4 * SZB);
    unsigned short* QTh = (unsigned short*)(ws + 4 * SZB + 16777216);
    unsigned short* QTl = QTh + 524288;
    unsigned short* VTh = QTl + 524288;
    unsigned short* VTl = VTh + 262144;
    float* w_buf = (float*)(VTl + 262144);
    float* p_buf = w_buf + 16384;
    float* wmax  = p_buf + 16384;
    float* partial = wmax + 64;
    int* count = (int*)(partial + 8192);
    int* cand  = count + 64;

    hipMemsetAsync(count, 0, 4, stream);
    hipMemsetAsync(w_buf, 0, 16384 * 4, stream);

    convx_k<<<8192, 256, 0, stream>>>(X, Xhi, Xlo);
    convw_k<<<3072, 256, 0, stream>>>(Wqk, Wv, QTh, QTl, VTh, VTl);

    // qk = X @ Wqk (3-term split) -> q fp32, km fp32, kmT bf16
    mfma_gemm<1, 3><<<dim3(128, 8, 1), 256, 0, stream>>>(
        Xhi, Xlo, QTh, QTl, nullptr, q_buf, km_buf, kmT, mask, 1024, 512);

    // v = X @ Wv (single-term bf16; |delta out| ~0.016 << 0.069 threshold)
    mfma_gemm<0, 1><<<dim3(128, 4, 1), 256, 0, stream>>>(
        Xhi, nullptr, VTh, nullptr, v_buf, nullptr, nullptr, nullptr, nullptr,
        512, 512);

    // w += rowsum(q .* (adj @ km)), counted-vmcnt pipeline, 512 blocks
    adj_gemm<<<dim3(64, 4, 2), 256, 0, stream>>>(adj, kmT, q_buf, w_buf);

    fixup_k<<<64, 256, 0, stream>>>(w_buf, mask);

    wmax_k<<<BB, 256, 0, stream>>>(w_buf, wmax);
    select_k<<<64, 256, 0, stream>>>(w_buf, wmax, count, cand);
    refine_k<<<dim3(64, 128, 1), 256, 0, stream>>>(q_buf, km_buf, adj, cand, count, partial);
    apply_k<<<1, 128, 0, stream>>>(cand, count, partial, mask, w_buf);

    softmax_k<<<BB, 1024, 0, stream>>>(w_buf, p_buf);
    scale_k<<<8192, 256, 0, stream>>>(v_buf, p_buf, out);
}

// Round 6
// 474.448 us; speedup vs baseline: 1.0822x; 1.0822x over previous
//
#include <hip/hip_runtime.h>
#include <math.h>

#define BB 2
#define NN 8192
#define DD 512

static const float INV_SCALE = 0.04419417382415922f; // 1/sqrt(512)

typedef short s16x8 __attribute__((ext_vector_type(8)));
typedef unsigned short u16x8 __attribute__((ext_vector_type(8)));
typedef float f32x4 __attribute__((ext_vector_type(4)));

#define AS1 __attribute__((address_space(1)))
#define AS3 __attribute__((address_space(3)))

__device__ __forceinline__ unsigned short bfbits(__bf16 h) {
    return __builtin_bit_cast(unsigned short, h);
}

__device__ __forceinline__ void gll16(const void* g, void* l) {
    __builtin_amdgcn_global_load_lds((const AS1 unsigned int*)g, (AS3 unsigned int*)l, 16, 0, 0);
}

// ---------------------------------------------------------------------------
// convX: X f32 -> Xhi, Xlo bf16 (hi = rne(x), lo = rne(x - hi))
// ---------------------------------------------------------------------------
__global__ __launch_bounds__(256) void convx_k(
    const float* __restrict__ X, unsigned short* __restrict__ Xhi,
    unsigned short* __restrict__ Xlo)
{
    long i = (long)blockIdx.x * 256 + threadIdx.x;   // float4 index
    float4 x = ((const float4*)X)[i];
    __bf16 h0 = (__bf16)x.x, h1 = (__bf16)x.y, h2 = (__bf16)x.z, h3 = (__bf16)x.w;
    ushort4 hi4 = make_ushort4(bfbits(h0), bfbits(h1), bfbits(h2), bfbits(h3));
    __bf16 l0 = (__bf16)(x.x - (float)h0), l1 = (__bf16)(x.y - (float)h1);
    __bf16 l2 = (__bf16)(x.z - (float)h2), l3 = (__bf16)(x.w - (float)h3);
    ushort4 lo4 = make_ushort4(bfbits(l0), bfbits(l1), bfbits(l2), bfbits(l3));
    ((ushort4*)Xhi)[i] = hi4;
    ((ushort4*)Xlo)[i] = lo4;
}

// ---------------------------------------------------------------------------
// convW: Wqk (512x1024) -> WqkT hi/lo (1024x512 bf16); Wv (512x512) -> WvT hi
// ---------------------------------------------------------------------------
__global__ __launch_bounds__(256) void convw_k(
    const float* __restrict__ Wqk, const float* __restrict__ Wv,
    unsigned short* __restrict__ QTh, unsigned short* __restrict__ QTl,
    unsigned short* __restrict__ VTh, unsigned short* __restrict__ VTl)
{
    int i = blockIdx.x * 256 + threadIdx.x;          // < 786432
    float val; unsigned short *ph, *pl;
    if (i < 524288) {
        int n = i >> 9, k = i & 511;
        val = Wqk[k * 1024 + n]; ph = QTh + i; pl = QTl + i;
    } else {
        int o = i - 524288; int n = o >> 9, k = o & 511;
        val = Wv[k * 512 + n]; ph = VTh + o; pl = VTl + o;
    }
    __bf16 h = (__bf16)val;
    __bf16 l = (__bf16)(val - (float)h);
    *ph = bfbits(h); *pl = bfbits(l);
}

// ---------------------------------------------------------------------------
// qkv MFMA GEMM (round-3 structure, BK=32, dbuf, swizzled, __syncthreads).
// EPI 0: fp32 C.  EPI 1: qk split (q fp32 / km fp32 + kmT bf16).
// ---------------------------------------------------------------------------
template <int EPI, int NT>
__global__ __launch_bounds__(256, 2) void mfma_gemm(
    const unsigned short* __restrict__ A0, const unsigned short* __restrict__ A1,
    const unsigned short* __restrict__ B0, const unsigned short* __restrict__ B1,
    float* __restrict__ C,
    float* __restrict__ q, float* __restrict__ km,
    unsigned short* __restrict__ kmT, const float* __restrict__ mask,
    int N, int K)
{
    constexpr int BK = 32;
    constexpr int TILE_SH = 128 * BK;

    __shared__ unsigned short Asm[2 * TILE_SH];
    __shared__ unsigned short Bsm[2 * TILE_SH];

    const int t = threadIdx.x;
    const int wv = t >> 6, lane = t & 63;
    const int wm = wv >> 1, wn = wv & 1;
    const long m0 = blockIdx.x * 128;
    const int n0 = blockIdx.y * 128;

    f32x4 acc[4][4];
#pragma unroll
    for (int i = 0; i < 4; ++i)
#pragma unroll
        for (int j = 0; j < 4; ++j) acc[i][j] = {0.f, 0.f, 0.f, 0.f};

    const int swzcol = ((lane & 3) ^ ((lane >> 2) & 3)) * 16;   // byte offset
    auto stageA16 = [&](int term, int k0, int buf) {
        const unsigned short* Ab = (term < 2) ? A0 : A1;
#pragma unroll
        for (int u = 0; u < 2; ++u) {
            int c = wv * 2 + u;                       // chunk 0..7
            int row = c * 16 + (lane >> 2);
            gll16((const char*)Ab + ((m0 + row) * (long)K + k0) * 2 + swzcol,
                  (char*)Asm + buf * (TILE_SH * 2) + c * 1024);
        }
    };
    auto stageB16 = [&](int term, int k0, int buf) {
        const unsigned short* Bb = (NT == 3 && term == 1) ? B1 : B0;
#pragma unroll
        for (int u = 0; u < 2; ++u) {
            int c = wv * 2 + u;
            int row = c * 16 + (lane >> 2);
            gll16((const char*)Bb + ((long)(n0 + row) * K + k0) * 2 + swzcol,
                  (char*)Bsm + buf * (TILE_SH * 2) + c * 1024);
        }
    };

    stageA16(0, 0, 0);
    stageB16(0, 0, 0);
    __syncthreads();

    const int NTILES = NT * (K / BK);
    int cur = 0, term = 0, k0 = 0;
    const int g = lane >> 4;

#pragma unroll 2
    for (int tt = 0; tt < NTILES; ++tt) {
        int k0n = k0 + BK, termn = term;
        if (k0n == K) { k0n = 0; ++termn; }
        const bool hasNext = (tt + 1 < NTILES);

        if (hasNext) {
            stageA16(termn, k0n, cur ^ 1);
            stageB16(termn, k0n, cur ^ 1);
        }

        s16x8 av[4], bv[4];
#pragma unroll
        for (int f = 0; f < 4; ++f) {
            int ra = wm * 64 + f * 16 + (lane & 15);
            int rb = wn * 64 + f * 16 + (lane & 15);
            av[f] = *(const s16x8*)(Asm + cur * TILE_SH + ra * BK + ((g ^ (ra & 3)) << 3));
            bv[f] = *(const s16x8*)(Bsm + cur * TILE_SH + rb * BK + ((g ^ (rb & 3)) << 3));
        }
#pragma unroll
        for (int fm = 0; fm < 4; ++fm)
#pragma unroll
            for (int fn = 0; fn < 4; ++fn)
                acc[fm][fn] = __builtin_amdgcn_mfma_f32_16x16x32_bf16(
                    av[fm], bv[fn], acc[fm][fn], 0, 0, 0);

        __syncthreads();
        cur ^= 1; term = termn; k0 = k0n;
    }

    const long rbase = m0 + wm * 64;
    const int cbase = n0 + wn * 64;

    if constexpr (EPI == 0) {
#pragma unroll
        for (int fm = 0; fm < 4; ++fm) {
            long rb = rbase + fm * 16 + ((lane >> 4) << 2);
#pragma unroll
            for (int fn = 0; fn < 4; ++fn) {
                int c = cbase + fn * 16 + (lane & 15);
#pragma unroll
                for (int j = 0; j < 4; ++j)
                    C[(rb + j) * (long)N + c] = acc[fm][fn][j];
            }
        }
    } else {
        const bool isq = (n0 < 512);
#pragma unroll
        for (int fm = 0; fm < 4; ++fm) {
            long rb = rbase + fm * 16 + ((lane >> 4) << 2);
#pragma unroll
            for (int fn = 0; fn < 4; ++fn) {
                int c = cbase + fn * 16 + (lane & 15);
                if (isq) {
#pragma unroll
                    for (int j = 0; j < 4; ++j)
                        q[(rb + j) * 512L + c] = acc[fm][fn][j];
                } else {
                    int c2 = c - 512;
                    float kv[4];
#pragma unroll
                    for (int j = 0; j < 4; ++j) {
                        kv[j] = acc[fm][fn][j] * mask[rb + j];
                        km[(rb + j) * 512L + c2] = kv[j];
                    }
                    ushort4 pk = make_ushort4(bfbits((__bf16)kv[0]), bfbits((__bf16)kv[1]),
                                              bfbits((__bf16)kv[2]), bfbits((__bf16)kv[3]));
                    long b = rb >> 13, r = rb & 8191;
                    *(ushort4*)(kmT + (b << 22) + ((long)c2 << 13) + r) = pk;
                }
            }
        }
    }
}

// ---------------------------------------------------------------------------
// Big GEMM, adj read ONCE: BM=64, BN=512 (full N), BK=64.
// 512 threads = 8 waves; wave wv owns cols [wv*64, wv*64+64).
// LDS: A dbuf 2x8KB (adj f32 reg-staged -> bf16, XOR-swizzled ds_write),
//      B dbuf 2x64KB (kmT via global_load_lds, pre-swizzled source).
// Compiler-managed waits (__syncthreads), issue-early/commit-late A.
// Fused epilogue: w[r] += sum_c q[r,c] * C[r,c]  (atomicAdd, w pre-zeroed).
// Grid 256 blocks (1/CU), bijective XCD swizzle for kmT L2 locality.
// ---------------------------------------------------------------------------
__global__ __launch_bounds__(512, 1) void adj_gemm(
    const float* __restrict__ adj,          // [B][8192][8192]
    const unsigned short* __restrict__ kmT, // [B][512][8192] bf16 (B^T)
    const float* __restrict__ q,            // [B*8192][512]
    float* __restrict__ w)                  // [B*8192] (atomic accum)
{
    constexpr int NT = NN / 64;             // 128 K-steps
    __shared__ unsigned short Asm[2 * 64 * 64];    // 16 KB
    __shared__ unsigned short Bsm[2 * 512 * 64];   // 128 KB

    const int t = threadIdx.x;
    const int wv = t >> 6, lane = t & 63;

    // bijective XCD swizzle (256 = 8*32): XCD k gets 32 consecutive stripes
    const int bid = (int)blockIdx.x;
    const int lid = (bid & 7) * 32 + (bid >> 3);
    const int x = lid & 127, z = lid >> 7;
    const long m0 = (long)x * 64;

    const float* Az = adj + (long)z * NN * NN;
    const unsigned short* Bz = kmT + ((long)z << 22);

    f32x4 acc[4][4];   // [fm over 64 rows][fn over wave's 64 cols]
#pragma unroll
    for (int i = 0; i < 4; ++i)
#pragma unroll
        for (int j = 0; j < 4; ++j) acc[i][j] = {0.f, 0.f, 0.f, 0.f};

    // ---- B staging: 64 chunks of 1KB (8 d-rows x 128B), 8 per wave ----
    const int bswz = ((lane & 7) ^ (lane >> 3)) << 4;   // pre-swizzled src byte
    auto stageB = [&](int tt, int buf) {
        const long k0 = (long)tt * 64;
#pragma unroll
        for (int u = 0; u < 8; ++u) {
            int c = wv * 8 + u;                  // 0..63
            int d = c * 8 + (lane >> 3);         // 0..511
            gll16((const char*)Bz + ((long)d * NN + k0) * 2 + bswz,
                  (char*)Bsm + buf * 65536 + c * 1024);
        }
    };

    // ---- A staging: 64x64 f32 -> 2 float4/thread -> bf16 swizzled ds_write
    const int arow = t >> 3;                     // 0..63
    const int ac8  = t & 7;                      // 16B slot 0..7
    auto issueA = [&](int tt, float4 (&r)[2]) {
        const float* s = Az + (m0 + arow) * (long)NN + (long)tt * 64 + ac8 * 8;
        r[0] = *(const float4*)s;
        r[1] = *(const float4*)(s + 4);
    };
    auto commitA = [&](float4 (&r)[2], int buf) {
        float4 a = r[0], b = r[1];
        u16x8 pk;
        pk[0] = bfbits((__bf16)a.x); pk[1] = bfbits((__bf16)a.y);
        pk[2] = bfbits((__bf16)a.z); pk[3] = bfbits((__bf16)a.w);
        pk[4] = bfbits((__bf16)b.x); pk[5] = bfbits((__bf16)b.y);
        pk[6] = bfbits((__bf16)b.z); pk[7] = bfbits((__bf16)b.w);
        *(u16x8*)(Asm + buf * 4096 + arow * 64 + ((ac8 ^ (arow & 7)) << 3)) = pk;
    };

    const int g = lane >> 4;
    auto compute = [&](int buf) {
#pragma unroll
        for (int ks = 0; ks < 2; ++ks) {
            s16x8 av[4], bv[4];
#pragma unroll
            for (int f = 0; f < 4; ++f) {
                int ma = f * 16 + (lane & 15);               // 0..63
                int nb = wv * 64 + f * 16 + (lane & 15);     // 0..511
                av[f] = *(const s16x8*)(Asm + buf * 4096 + ma * 64
                         + (((g + ks * 4) ^ (ma & 7)) << 3));
                bv[f] = *(const s16x8*)(Bsm + buf * 32768 + nb * 64
                         + (((g + ks * 4) ^ (nb & 7)) << 3));
            }
#pragma unroll
            for (int fm = 0; fm < 4; ++fm)
#pragma unroll
                for (int fn = 0; fn < 4; ++fn)
                    acc[fm][fn] = __builtin_amdgcn_mfma_f32_16x16x32_bf16(
                        av[fm], bv[fn], acc[fm][fn], 0, 0, 0);
        }
    };

    float4 rA[2];
    issueA(0, rA);
    stageB(0, 0);
    commitA(rA, 0);
    __syncthreads();

#pragma unroll 2
    for (int tt = 0; tt < NT; ++tt) {
        const int cur = tt & 1;
        const bool hasNext = (tt + 1 < NT);
        if (hasNext) {
            issueA(tt + 1, rA);          // HBM loads in flight over compute
            stageB(tt + 1, cur ^ 1);
        }
        compute(cur);
        if (hasNext) commitA(rA, cur ^ 1);
        __syncthreads();
    }

    // ---- fused epilogue: w[r] += sum_c q[r,c] * C[r,c] ----
    const long zrow = (long)z * NN;
#pragma unroll
    for (int fm = 0; fm < 4; ++fm) {
#pragma unroll
        for (int j = 0; j < 4; ++j) {
            long r = zrow + m0 + fm * 16 + ((lane >> 4) << 2) + j;
            const float* qr = q + r * 512L + wv * 64 + (lane & 15);
            float s = 0.f;
#pragma unroll
            for (int fn = 0; fn < 4; ++fn)
                s += qr[fn * 16] * acc[fm][fn][j];
            s += __shfl_xor(s, 1); s += __shfl_xor(s, 2);
            s += __shfl_xor(s, 4); s += __shfl_xor(s, 8);
            if ((lane & 15) == 0) atomicAdd(w + r, s);
        }
    }
}

// ---------------------------------------------------------------------------
__global__ __launch_bounds__(256) void fixup_k(
    float* __restrict__ w, const float* __restrict__ mask)
{
    int i = blockIdx.x * 256 + threadIdx.x;
    w[i] *= INV_SCALE * mask[i];
}

// ---------------------------------------------------------------------------
// Refinement: exact fp32 recompute of w for rows near the max.
// ---------------------------------------------------------------------------
__global__ __launch_bounds__(256) void wmax_k(const float* __restrict__ w,
                                              float* __restrict__ wmax)
{
    const int b = blockIdx.x;
    const float* wr = w + (long)b * NN;
    const int t = threadIdx.x;
    float m = -3.4e38f;
    for (int i = t; i < NN; i += 256) m = fmaxf(m, wr[i]);
#pragma unroll
    for (int o = 32; o > 0; o >>= 1) m = fmaxf(m, __shfl_down(m, o));
    __shared__ float red[4];
    if ((t & 63) == 0) red[t >> 6] = m;
    __syncthreads();
    if (t == 0) wmax[b] = fmaxf(fmaxf(red[0], red[1]), fmaxf(red[2], red[3]));
}

__global__ __launch_bounds__(256) void select_k(
    const float* __restrict__ w, const float* __restrict__ wmax,
    int* __restrict__ count, int* __restrict__ cand)
{
    int i = blockIdx.x * 256 + threadIdx.x;  // 16384
    int b = i >> 13;
    if (w[i] >= wmax[b] - 15.f) {
        int p = atomicAdd(count, 1);
        if (p < 128) cand[p] = i;
    }
}

__global__ __launch_bounds__(256) void refine_k(
    const float* __restrict__ q, const float* __restrict__ km,
    const float* __restrict__ adj, const int* __restrict__ cand,
    const int* __restrict__ count, float* __restrict__ partial)
{
    int y = blockIdx.y;
    int cnt = *count; if (cnt > 128) cnt = 128;
    if (y >= cnt) return;
    const int row = cand[y];
    const int b = row >> 13, r = row & 8191;
    const int x = blockIdx.x;
    const int t = threadIdx.x, w = t >> 6, l = t & 63;

    const float* qr = q + (long)row * 512 + l * 8;
    const float4 q0 = *(const float4*)qr;
    const float4 q1 = *(const float4*)(qr + 4);
    const float* kmB = km + ((long)b << 13) * 512;
    const float* adjR = adj + (((long)b << 13) + r) * 8192L;

    float acc = 0.f;
    const int jbase = x * 128 + w * 32;
    for (int i = 0; i < 32; ++i) {
        int j = jbase + i;
        const float* kr = kmB + (long)j * 512 + l * 8;
        const float4 k0 = *(const float4*)kr;
        const float4 k1 = *(const float4*)(kr + 4);
        float d = q0.x * k0.x + q0.y * k0.y + q0.z * k0.z + q0.w * k0.w
                + q1.x * k1.x + q1.y * k1.y + q1.z * k1.z + q1.w * k1.w;
#pragma unroll
        for (int o = 32; o > 0; o >>= 1) d += __shfl_down(d, o);
        if (l == 0) acc += adjR[j] * d;
    }
    __shared__ float red[4];
    if (l == 0) red[w] = acc;
    __syncthreads();
    if (t == 0) partial[y * 64 + x] = red[0] + red[1] + red[2] + red[3];
}

__global__ __launch_bounds__(128) void apply_k(
    const int* __restrict__ cand, const int* __restrict__ count,
    const float* __restrict__ partial, const float* __restrict__ mask,
    float* __restrict__ w)
{
    int t = threadIdx.x;
    int cnt = *count; if (cnt > 128) cnt = 128;
    if (t < cnt) {
        float s = 0.f;
        for (int x = 0; x < 64; ++x) s += partial[t * 64 + x];
        int row = cand[t];
        w[row] = s * INV_SCALE * mask[row];
    }
}

// ---------------------------------------------------------------------------
__global__ __launch_bounds__(1024) void softmax_k(
    const float* __restrict__ w, float* __restrict__ p)
{
    const int b = blockIdx.x;
    const float* wr = w + (long)b * NN;
    float* pr = p + (long)b * NN;
    const int t = threadIdx.x;
    __shared__ float red[16];
    __shared__ float bmax, bsum;

    float m = -3.4e38f;
    for (int i = t; i < NN; i += 1024) m = fmaxf(m, wr[i]);
#pragma unroll
    for (int o = 32; o > 0; o >>= 1) m = fmaxf(m, __shfl_down(m, o));
    if ((t & 63) == 0) red[t >> 6] = m;
    __syncthreads();
    if (t == 0) {
        float mm = red[0];
        for (int i = 1; i < 16; ++i) mm = fmaxf(mm, red[i]);
        bmax = mm;
    }
    __syncthreads();
    const float M = bmax;

    float s = 0.f;
    for (int i = t; i < NN; i += 1024) s += expf(wr[i] - M);
#pragma unroll
    for (int o = 32; o > 0; o >>= 1) s += __shfl_down(s, o);
    __syncthreads();
    if ((t & 63) == 0) red[t >> 6] = s;
    __syncthreads();
    if (t == 0) {
        float ss = 0.f;
        for (int i = 0; i < 16; ++i) ss += red[i];
        bsum = ss;
    }
    __syncthreads();
    const float invS = 1.f / bsum;
    for (int i = t; i < NN; i += 1024) pr[i] = expf(wr[i] - M) * invS;
}

__global__ __launch_bounds__(256) void scale_k(
    const float* __restrict__ v, const float* __restrict__ p,
    float* __restrict__ out)
{
    const long i = (long)blockIdx.x * 256 + threadIdx.x;  // float4 index
    const int row = (int)(i >> 7);
    const float pv = p[row];
    float4 vv = ((const float4*)v)[i];
    vv.x *= pv; vv.y *= pv; vv.z *= pv; vv.w *= pv;
    ((float4*)out)[i] = vv;
}

// ---------------------------------------------------------------------------
extern "C" void kernel_launch(void* const* d_in, const int* in_sizes, int n_in,
                              void* d_out, int out_size, void* d_ws, size_t ws_size,
                              hipStream_t stream)
{
    const float* X    = (const float*)d_in[0];
    const float* adj  = (const float*)d_in[1];
    const float* mask = (const float*)d_in[2];
    const float* Wqk  = (const float*)d_in[3];
    const float* Wv   = (const float*)d_in[4];
    float* out = (float*)d_out;

    char* ws = (char*)d_ws;
    const long SZB = 33554432;  // 16384*512*4 bytes
    float* q_buf  = (float*)(ws);
    float* km_buf = (float*)(ws + SZB);
    float* v_buf  = (float*)(ws + 2 * SZB);
    unsigned short* Xhi = (unsigned short*)(ws + 3 * SZB);
    unsigned short* Xlo = Xhi + 8388608;
    unsigned short* kmT = (unsigned short*)(ws + 4 * SZB);
    unsigned short* QTh = (unsigned short*)(ws + 4 * SZB + 16777216);
    unsigned short* QTl = QTh + 524288;
    unsigned short* VTh = QTl + 524288;
    unsigned short* VTl = VTh + 262144;
    float* w_buf = (float*)(VTl + 262144);
    float* p_buf = w_buf + 16384;
    float* wmax  = p_buf + 16384;
    float* partial = wmax + 64;
    int* count = (int*)(partial + 8192);
    int* cand  = count + 64;

    hipMemsetAsync(count, 0, 4, stream);
    hipMemsetAsync(w_buf, 0, 16384 * 4, stream);

    convx_k<<<8192, 256, 0, stream>>>(X, Xhi, Xlo);
    convw_k<<<3072, 256, 0, stream>>>(Wqk, Wv, QTh, QTl, VTh, VTl);

    // qk = X @ Wqk (3-term split) -> q fp32, km fp32, kmT bf16
    mfma_gemm<1, 3><<<dim3(128, 8, 1), 256, 0, stream>>>(
        Xhi, Xlo, QTh, QTl, nullptr, q_buf, km_buf, kmT, mask, 1024, 512);

    // v = X @ Wv (single-term bf16; |delta out| ~0.016 << 0.069 threshold)
    mfma_gemm<0, 1><<<dim3(128, 4, 1), 256, 0, stream>>>(
        Xhi, nullptr, VTh, nullptr, v_buf, nullptr, nullptr, nullptr, nullptr,
        512, 512);

    // w += rowsum(q .* (adj @ km)), adj read once (BN=512 full-N blocking)
    adj_gemm<<<256, 512, 0, stream>>>(adj, kmT, q_buf, w_buf);

    fixup_k<<<64, 256, 0, stream>>>(w_buf, mask);

    wmax_k<<<BB, 256, 0, stream>>>(w_buf, wmax);
    select_k<<<64, 256, 0, stream>>>(w_buf, wmax, count, cand);
    refine_k<<<dim3(64, 128, 1), 256, 0, stream>>>(q_buf, km_buf, adj, cand, count, partial);
    apply_k<<<1, 128, 0, stream>>>(cand, count, partial, mask, w_buf);

    softmax_k<<<BB, 1024, 0, stream>>>(w_buf, p_buf);
    scale_k<<<8192, 256, 0, stream>>>(v_buf, p_buf, out);
}

// Round 7
// 447.810 us; speedup vs baseline: 1.1466x; 1.0595x over previous
//
#include <hip/hip_runtime.h>
#include <math.h>

#define BB 2
#define NN 8192
#define DD 512

static const float INV_SCALE = 0.04419417382415922f; // 1/sqrt(512)

typedef short s16x8 __attribute__((ext_vector_type(8)));
typedef unsigned short u16x8 __attribute__((ext_vector_type(8)));
typedef float f32x4 __attribute__((ext_vector_type(4)));

#define AS1 __attribute__((address_space(1)))
#define AS3 __attribute__((address_space(3)))

__device__ __forceinline__ unsigned short bfbits(__bf16 h) {
    return __builtin_bit_cast(unsigned short, h);
}

__device__ __forceinline__ void gll16(const void* g, void* l) {
    __builtin_amdgcn_global_load_lds((const AS1 unsigned int*)g, (AS3 unsigned int*)l, 16, 0, 0);
}

// ---------------------------------------------------------------------------
// convX: X f32 -> Xhi, Xlo bf16 (hi = rne(x), lo = rne(x - hi))
// ---------------------------------------------------------------------------
__global__ __launch_bounds__(256) void convx_k(
    const float* __restrict__ X, unsigned short* __restrict__ Xhi,
    unsigned short* __restrict__ Xlo)
{
    long i = (long)blockIdx.x * 256 + threadIdx.x;   // float4 index
    float4 x = ((const float4*)X)[i];
    __bf16 h0 = (__bf16)x.x, h1 = (__bf16)x.y, h2 = (__bf16)x.z, h3 = (__bf16)x.w;
    ushort4 hi4 = make_ushort4(bfbits(h0), bfbits(h1), bfbits(h2), bfbits(h3));
    __bf16 l0 = (__bf16)(x.x - (float)h0), l1 = (__bf16)(x.y - (float)h1);
    __bf16 l2 = (__bf16)(x.z - (float)h2), l3 = (__bf16)(x.w - (float)h3);
    ushort4 lo4 = make_ushort4(bfbits(l0), bfbits(l1), bfbits(l2), bfbits(l3));
    ((ushort4*)Xhi)[i] = hi4;
    ((ushort4*)Xlo)[i] = lo4;
}

// ---------------------------------------------------------------------------
// convW: Wqk (512x1024) -> WqkT hi/lo (1024x512 bf16); Wv (512x512) -> WvT hi
// ---------------------------------------------------------------------------
__global__ __launch_bounds__(256) void convw_k(
    const float* __restrict__ Wqk, const float* __restrict__ Wv,
    unsigned short* __restrict__ QTh, unsigned short* __restrict__ QTl,
    unsigned short* __restrict__ VTh, unsigned short* __restrict__ VTl)
{
    int i = blockIdx.x * 256 + threadIdx.x;          // < 786432
    float val; unsigned short *ph, *pl;
    if (i < 524288) {
        int n = i >> 9, k = i & 511;
        val = Wqk[k * 1024 + n]; ph = QTh + i; pl = QTl + i;
    } else {
        int o = i - 524288; int n = o >> 9, k = o & 511;
        val = Wv[k * 512 + n]; ph = VTh + o; pl = VTl + o;
    }
    __bf16 h = (__bf16)val;
    __bf16 l = (__bf16)(val - (float)h);
    *ph = bfbits(h); *pl = bfbits(l);
}

// ---------------------------------------------------------------------------
// qkv MFMA GEMM (round-3 structure, BK=32, dbuf, swizzled, __syncthreads).
// EPI 0: fp32 C.  EPI 1: qk split (q fp32 / km fp32 + kmT bf16).
// ---------------------------------------------------------------------------
template <int EPI, int NT>
__global__ __launch_bounds__(256, 2) void mfma_gemm(
    const unsigned short* __restrict__ A0, const unsigned short* __restrict__ A1,
    const unsigned short* __restrict__ B0, const unsigned short* __restrict__ B1,
    float* __restrict__ C,
    float* __restrict__ q, float* __restrict__ km,
    unsigned short* __restrict__ kmT, const float* __restrict__ mask,
    int N, int K)
{
    constexpr int BK = 32;
    constexpr int TILE_SH = 128 * BK;

    __shared__ unsigned short Asm[2 * TILE_SH];
    __shared__ unsigned short Bsm[2 * TILE_SH];

    const int t = threadIdx.x;
    const int wv = t >> 6, lane = t & 63;
    const int wm = wv >> 1, wn = wv & 1;
    const long m0 = blockIdx.x * 128;
    const int n0 = blockIdx.y * 128;

    f32x4 acc[4][4];
#pragma unroll
    for (int i = 0; i < 4; ++i)
#pragma unroll
        for (int j = 0; j < 4; ++j) acc[i][j] = {0.f, 0.f, 0.f, 0.f};

    const int swzcol = ((lane & 3) ^ ((lane >> 2) & 3)) * 16;   // byte offset
    auto stageA16 = [&](int term, int k0, int buf) {
        const unsigned short* Ab = (term < 2) ? A0 : A1;
#pragma unroll
        for (int u = 0; u < 2; ++u) {
            int c = wv * 2 + u;                       // chunk 0..7
            int row = c * 16 + (lane >> 2);
            gll16((const char*)Ab + ((m0 + row) * (long)K + k0) * 2 + swzcol,
                  (char*)Asm + buf * (TILE_SH * 2) + c * 1024);
        }
    };
    auto stageB16 = [&](int term, int k0, int buf) {
        const unsigned short* Bb = (NT == 3 && term == 1) ? B1 : B0;
#pragma unroll
        for (int u = 0; u < 2; ++u) {
            int c = wv * 2 + u;
            int row = c * 16 + (lane >> 2);
            gll16((const char*)Bb + ((long)(n0 + row) * K + k0) * 2 + swzcol,
                  (char*)Bsm + buf * (TILE_SH * 2) + c * 1024);
        }
    };

    stageA16(0, 0, 0);
    stageB16(0, 0, 0);
    __syncthreads();

    const int NTILES = NT * (K / BK);
    int cur = 0, term = 0, k0 = 0;
    const int g = lane >> 4;

#pragma unroll 2
    for (int tt = 0; tt < NTILES; ++tt) {
        int k0n = k0 + BK, termn = term;
        if (k0n == K) { k0n = 0; ++termn; }
        const bool hasNext = (tt + 1 < NTILES);

        if (hasNext) {
            stageA16(termn, k0n, cur ^ 1);
            stageB16(termn, k0n, cur ^ 1);
        }

        s16x8 av[4], bv[4];
#pragma unroll
        for (int f = 0; f < 4; ++f) {
            int ra = wm * 64 + f * 16 + (lane & 15);
            int rb = wn * 64 + f * 16 + (lane & 15);
            av[f] = *(const s16x8*)(Asm + cur * TILE_SH + ra * BK + ((g ^ (ra & 3)) << 3));
            bv[f] = *(const s16x8*)(Bsm + cur * TILE_SH + rb * BK + ((g ^ (rb & 3)) << 3));
        }
#pragma unroll
        for (int fm = 0; fm < 4; ++fm)
#pragma unroll
            for (int fn = 0; fn < 4; ++fn)
                acc[fm][fn] = __builtin_amdgcn_mfma_f32_16x16x32_bf16(
                    av[fm], bv[fn], acc[fm][fn], 0, 0, 0);

        __syncthreads();
        cur ^= 1; term = termn; k0 = k0n;
    }

    const long rbase = m0 + wm * 64;
    const int cbase = n0 + wn * 64;

    if constexpr (EPI == 0) {
#pragma unroll
        for (int fm = 0; fm < 4; ++fm) {
            long rb = rbase + fm * 16 + ((lane >> 4) << 2);
#pragma unroll
            for (int fn = 0; fn < 4; ++fn) {
                int c = cbase + fn * 16 + (lane & 15);
#pragma unroll
                for (int j = 0; j < 4; ++j)
                    C[(rb + j) * (long)N + c] = acc[fm][fn][j];
            }
        }
    } else {
        const bool isq = (n0 < 512);
#pragma unroll
        for (int fm = 0; fm < 4; ++fm) {
            long rb = rbase + fm * 16 + ((lane >> 4) << 2);
#pragma unroll
            for (int fn = 0; fn < 4; ++fn) {
                int c = cbase + fn * 16 + (lane & 15);
                if (isq) {
#pragma unroll
                    for (int j = 0; j < 4; ++j)
                        q[(rb + j) * 512L + c] = acc[fm][fn][j];
                } else {
                    int c2 = c - 512;
                    float kv[4];
#pragma unroll
                    for (int j = 0; j < 4; ++j) {
                        kv[j] = acc[fm][fn][j] * mask[rb + j];
                        km[(rb + j) * 512L + c2] = kv[j];
                    }
                    ushort4 pk = make_ushort4(bfbits((__bf16)kv[0]), bfbits((__bf16)kv[1]),
                                              bfbits((__bf16)kv[2]), bfbits((__bf16)kv[3]));
                    long b = rb >> 13, r = rb & 8191;
                    *(ushort4*)(kmT + (b << 22) + ((long)c2 << 13) + r) = pk;
                }
            }
        }
    }
}

// ---------------------------------------------------------------------------
// Big GEMM: BM=64, BN=256, BK=64 — adj read ~once (paired n-blocks share the
// panel via same-XCD L2), AND 2 blocks/CU for TLP across the barrier drain.
// 256 threads = 4 waves; wave wv owns cols [wv*64, wv*64+64).
// LDS 80 KB: A dbuf 2x8KB (adj f32 reg-staged -> bf16, XOR-swizzled write),
//            B dbuf 2x32KB (kmT via global_load_lds, pre-swizzled source).
// Compiler-managed waits (__syncthreads), issue-early/commit-late A.
// Fused epilogue: w[r] += sum_c q[r,c] * C[r,c]  (atomicAdd, w pre-zeroed).
// Grid 512; swizzle lid=(bid&7)*64+(bid>>3): pair (2p,2p+1) lands on one XCD
// 8 dispatch-slots apart -> co-resident, second adj read is an L2 hit.
// ---------------------------------------------------------------------------
__global__ __launch_bounds__(256, 2) void adj_gemm(
    const float* __restrict__ adj,          // [B][8192][8192]
    const unsigned short* __restrict__ kmT, // [B][512][8192] bf16 (B^T)
    const float* __restrict__ q,            // [B*8192][512]
    float* __restrict__ w)                  // [B*8192] (atomic accum)
{
    constexpr int NT = NN / 64;             // 128 K-steps
    __shared__ unsigned short Asm[2 * 64 * 64];    // 16 KB
    __shared__ unsigned short Bsm[2 * 256 * 64];   // 64 KB

    const int t = threadIdx.x;
    const int wv = t >> 6, lane = t & 63;

    const int bid = (int)blockIdx.x;
    const int lid = (bid & 7) * 64 + (bid >> 3);   // 512 blocks, bijective
    const int n  = lid & 1;                        // n-half of the panel
    const int x  = (lid >> 1) & 127;               // m-tile
    const int z  = lid >> 8;                       // batch
    const long m0 = (long)x * 64;
    const int n0 = n * 256;

    const float* Az = adj + (long)z * NN * NN;
    const unsigned short* Bz = kmT + ((long)z << 22);

    f32x4 acc[4][4];   // [fm over 64 rows][fn over wave's 64 cols]
#pragma unroll
    for (int i = 0; i < 4; ++i)
#pragma unroll
        for (int j = 0; j < 4; ++j) acc[i][j] = {0.f, 0.f, 0.f, 0.f};

    // ---- B staging: 32 chunks of 1KB (8 d-rows x 128B), 8 per wave ----
    const int bswz = ((lane & 7) ^ (lane >> 3)) << 4;   // pre-swizzled src byte
    auto stageB = [&](int tt, int buf) {
        const long k0 = (long)tt * 64;
#pragma unroll
        for (int u = 0; u < 8; ++u) {
            int c = wv * 8 + u;                  // 0..31
            int d = n0 + c * 8 + (lane >> 3);    // global col row 0..511
            gll16((const char*)Bz + ((long)d * NN + k0) * 2 + bswz,
                  (char*)Bsm + buf * 32768 + c * 1024);
        }
    };

    // ---- A staging: 64x64 f32 -> 4 float4/thread -> bf16 swizzled ds_write
    const int arow = t >> 2;                     // 0..63
    const int asl0 = (t & 3) * 2;                // bf16 16B-slot base 0,2,4,6
    auto issueA = [&](int tt, float4 (&r)[4]) {
        const float* s = Az + (m0 + arow) * (long)NN + (long)tt * 64 + (t & 3) * 16;
        r[0] = *(const float4*)s;
        r[1] = *(const float4*)(s + 4);
        r[2] = *(const float4*)(s + 8);
        r[3] = *(const float4*)(s + 12);
    };
    auto commitA = [&](float4 (&r)[4], int buf) {
#pragma unroll
        for (int u = 0; u < 2; ++u) {
            float4 a = r[2 * u], b = r[2 * u + 1];
            u16x8 pk;
            pk[0] = bfbits((__bf16)a.x); pk[1] = bfbits((__bf16)a.y);
            pk[2] = bfbits((__bf16)a.z); pk[3] = bfbits((__bf16)a.w);
            pk[4] = bfbits((__bf16)b.x); pk[5] = bfbits((__bf16)b.y);
            pk[6] = bfbits((__bf16)b.z); pk[7] = bfbits((__bf16)b.w);
            *(u16x8*)(Asm + buf * 4096 + arow * 64
                      + (((asl0 + u) ^ (arow & 7)) << 3)) = pk;
        }
    };

    const int g = lane >> 4;
    auto compute = [&](int buf) {
#pragma unroll
        for (int ks = 0; ks < 2; ++ks) {
            s16x8 av[4], bv[4];
#pragma unroll
            for (int f = 0; f < 4; ++f) {
                int ma = f * 16 + (lane & 15);               // 0..63
                int nb = wv * 64 + f * 16 + (lane & 15);     // 0..255 local
                av[f] = *(const s16x8*)(Asm + buf * 4096 + ma * 64
                         + (((g + ks * 4) ^ (ma & 7)) << 3));
                bv[f] = *(const s16x8*)(Bsm + buf * 16384 + nb * 64
                         + (((g + ks * 4) ^ (nb & 7)) << 3));
            }
#pragma unroll
            for (int fm = 0; fm < 4; ++fm)
#pragma unroll
                for (int fn = 0; fn < 4; ++fn)
                    acc[fm][fn] = __builtin_amdgcn_mfma_f32_16x16x32_bf16(
                        av[fm], bv[fn], acc[fm][fn], 0, 0, 0);
        }
    };

    float4 rA[4];
    issueA(0, rA);
    stageB(0, 0);
    commitA(rA, 0);
    __syncthreads();

#pragma unroll 2
    for (int tt = 0; tt < NT; ++tt) {
        const int cur = tt & 1;
        const bool hasNext = (tt + 1 < NT);
        if (hasNext) {
            issueA(tt + 1, rA);          // HBM loads in flight over compute
            stageB(tt + 1, cur ^ 1);
        }
        compute(cur);
        if (hasNext) commitA(rA, cur ^ 1);
        __syncthreads();
    }

    // ---- fused epilogue: w[r] += sum_c q[r,c] * C[r,c] ----
    const long zrow = (long)z * NN;
#pragma unroll
    for (int fm = 0; fm < 4; ++fm) {
#pragma unroll
        for (int j = 0; j < 4; ++j) {
            long r = zrow + m0 + fm * 16 + ((lane >> 4) << 2) + j;
            const float* qr = q + r * 512L + n0 + wv * 64 + (lane & 15);
            float s = 0.f;
#pragma unroll
            for (int fn = 0; fn < 4; ++fn)
                s += qr[fn * 16] * acc[fm][fn][j];
            s += __shfl_xor(s, 1); s += __shfl_xor(s, 2);
            s += __shfl_xor(s, 4); s += __shfl_xor(s, 8);
            if ((lane & 15) == 0) atomicAdd(w + r, s);
        }
    }
}

// ---------------------------------------------------------------------------
__global__ __launch_bounds__(256) void fixup_k(
    float* __restrict__ w, const float* __restrict__ mask)
{
    int i = blockIdx.x * 256 + threadIdx.x;
    w[i] *= INV_SCALE * mask[i];
}

// ---------------------------------------------------------------------------
// Refinement: exact fp32 recompute of w for rows near the max.
// ---------------------------------------------------------------------------
__global__ __launch_bounds__(256) void wmax_k(const float* __restrict__ w,
                                              float* __restrict__ wmax)
{
    const int b = blockIdx.x;
    const float* wr = w + (long)b * NN;
    const int t = threadIdx.x;
    float m = -3.4e38f;
    for (int i = t; i < NN; i += 256) m = fmaxf(m, wr[i]);
#pragma unroll
    for (int o = 32; o > 0; o >>= 1) m = fmaxf(m, __shfl_down(m, o));
    __shared__ float red[4];
    if ((t & 63) == 0) red[t >> 6] = m;
    __syncthreads();
    if (t == 0) wmax[b] = fmaxf(fmaxf(red[0], red[1]), fmaxf(red[2], red[3]));
}

__global__ __launch_bounds__(256) void select_k(
    const float* __restrict__ w, const float* __restrict__ wmax,
    int* __restrict__ count, int* __restrict__ cand)
{
    int i = blockIdx.x * 256 + threadIdx.x;  // 16384
    int b = i >> 13;
    if (w[i] >= wmax[b] - 15.f) {
        int p = atomicAdd(count, 1);
        if (p < 128) cand[p] = i;
    }
}

__global__ __launch_bounds__(256) void refine_k(
    const float* __restrict__ q, const float* __restrict__ km,
    const float* __restrict__ adj, const int* __restrict__ cand,
    const int* __restrict__ count, float* __restrict__ partial)
{
    int y = blockIdx.y;
    int cnt = *count; if (cnt > 128) cnt = 128;
    if (y >= cnt) return;
    const int row = cand[y];
    const int b = row >> 13, r = row & 8191;
    const int x = blockIdx.x;
    const int t = threadIdx.x, w = t >> 6, l = t & 63;

    const float* qr = q + (long)row * 512 + l * 8;
    const float4 q0 = *(const float4*)qr;
    const float4 q1 = *(const float4*)(qr + 4);
    const float* kmB = km + ((long)b << 13) * 512;
    const float* adjR = adj + (((long)b << 13) + r) * 8192L;

    float acc = 0.f;
    const int jbase = x * 128 + w * 32;
    for (int i = 0; i < 32; ++i) {
        int j = jbase + i;
        const float* kr = kmB + (long)j * 512 + l * 8;
        const float4 k0 = *(const float4*)kr;
        const float4 k1 = *(const float4*)(kr + 4);
        float d = q0.x * k0.x + q0.y * k0.y + q0.z * k0.z + q0.w * k0.w
                + q1.x * k1.x + q1.y * k1.y + q1.z * k1.z + q1.w * k1.w;
#pragma unroll
        for (int o = 32; o > 0; o >>= 1) d += __shfl_down(d, o);
        if (l == 0) acc += adjR[j] * d;
    }
    __shared__ float red[4];
    if (l == 0) red[w] = acc;
    __syncthreads();
    if (t == 0) partial[y * 64 + x] = red[0] + red[1] + red[2] + red[3];
}

__global__ __launch_bounds__(128) void apply_k(
    const int* __restrict__ cand, const int* __restrict__ count,
    const float* __restrict__ partial, const float* __restrict__ mask,
    float* __restrict__ w)
{
    int t = threadIdx.x;
    int cnt = *count; if (cnt > 128) cnt = 128;
    if (t < cnt) {
        float s = 0.f;
        for (int x = 0; x < 64; ++x) s += partial[t * 64 + x];
        int row = cand[t];
        w[row] = s * INV_SCALE * mask[row];
    }
}

// ---------------------------------------------------------------------------
__global__ __launch_bounds__(1024) void softmax_k(
    const float* __restrict__ w, float* __restrict__ p)
{
    const int b = blockIdx.x;
    const float* wr = w + (long)b * NN;
    float* pr = p + (long)b * NN;
    const int t = threadIdx.x;
    __shared__ float red[16];
    __shared__ float bmax, bsum;

    float m = -3.4e38f;
    for (int i = t; i < NN; i += 1024) m = fmaxf(m, wr[i]);
#pragma unroll
    for (int o = 32; o > 0; o >>= 1) m = fmaxf(m, __shfl_down(m, o));
    if ((t & 63) == 0) red[t >> 6] = m;
    __syncthreads();
    if (t == 0) {
        float mm = red[0];
        for (int i = 1; i < 16; ++i) mm = fmaxf(mm, red[i]);
        bmax = mm;
    }
    __syncthreads();
    const float M = bmax;

    float s = 0.f;
    for (int i = t; i < NN; i += 1024) s += expf(wr[i] - M);
#pragma unroll
    for (int o = 32; o > 0; o >>= 1) s += __shfl_down(s, o);
    __syncthreads();
    if ((t & 63) == 0) red[t >> 6] = s;
    __syncthreads();
    if (t == 0) {
        float ss = 0.f;
        for (int i = 0; i < 16; ++i) ss += red[i];
        bsum = ss;
    }
    __syncthreads();
    const float invS = 1.f / bsum;
    for (int i = t; i < NN; i += 1024) pr[i] = expf(wr[i] - M) * invS;
}

__global__ __launch_bounds__(256) void scale_k(
    const float* __restrict__ v, const float* __restrict__ p,
    float* __restrict__ out)
{
    const long i = (long)blockIdx.x * 256 + threadIdx.x;  // float4 index
    const int row = (int)(i >> 7);
    const float pv = p[row];
    float4 vv = ((const float4*)v)[i];
    vv.x *= pv; vv.y *= pv; vv.z *= pv; vv.w *= pv;
    ((float4*)out)[i] = vv;
}

// ---------------------------------------------------------------------------
extern "C" void kernel_launch(void* const* d_in, const int* in_sizes, int n_in,
                              void* d_out, int out_size, void* d_ws, size_t ws_size,
                              hipStream_t stream)
{
    const float* X    = (const float*)d_in[0];
    const float* adj  = (const float*)d_in[1];
    const float* mask = (const float*)d_in[2];
    const float* Wqk  = (const float*)d_in[3];
    const float* Wv   = (const float*)d_in[4];
    float* out = (float*)d_out;

    char* ws = (char*)d_ws;
    const long SZB = 33554432;  // 16384*512*4 bytes
    float* q_buf  = (float*)(ws);
    float* km_buf = (float*)(ws + SZB);
    float* v_buf  = (float*)(ws + 2 * SZB);
    unsigned short* Xhi = (unsigned short*)(ws + 3 * SZB);
    unsigned short* Xlo = Xhi + 8388608;
    unsigned short* kmT = (unsigned short*)(ws + 4 * SZB);
    unsigned short* QTh = (unsigned short*)(ws + 4 * SZB + 16777216);
    unsigned short* QTl = QTh + 524288;
    unsigned short* VTh = QTl + 524288;
    unsigned short* VTl = VTh + 262144;
    float* w_buf = (float*)(VTl + 262144);
    float* p_buf = w_buf + 16384;
    float* wmax  = p_buf + 16384;
    float* partial = wmax + 64;
    int* count = (int*)(partial + 8192);
    int* cand  = count + 64;

    hipMemsetAsync(count, 0, 4, stream);
    hipMemsetAsync(w_buf, 0, 16384 * 4, stream);

    convx_k<<<8192, 256, 0, stream>>>(X, Xhi, Xlo);
    convw_k<<<3072, 256, 0, stream>>>(Wqk, Wv, QTh, QTl, VTh, VTl);

    // qk = X @ Wqk (3-term split) -> q fp32, km fp32, kmT bf16
    mfma_gemm<1, 3><<<dim3(128, 8, 1), 256, 0, stream>>>(
        Xhi, Xlo, QTh, QTl, nullptr, q_buf, km_buf, kmT, mask, 1024, 512);

    // v = X @ Wv (single-term bf16; |delta out| ~0.016 << 0.069 threshold)
    mfma_gemm<0, 1><<<dim3(128, 4, 1), 256, 0, stream>>>(
        Xhi, nullptr, VTh, nullptr, v_buf, nullptr, nullptr, nullptr, nullptr,
        512, 512);

    // w += rowsum(q .* (adj @ km)); adj ~once via paired-XCD L2, 2 blocks/CU
    adj_gemm<<<512, 256, 0, stream>>>(adj, kmT, q_buf, w_buf);

    fixup_k<<<64, 256, 0, stream>>>(w_buf, mask);

    wmax_k<<<BB, 256, 0, stream>>>(w_buf, wmax);
    select_k<<<64, 256, 0, stream>>>(w_buf, wmax, count, cand);
    refine_k<<<dim3(64, 128, 1), 256, 0, stream>>>(q_buf, km_buf, adj, cand, count, partial);
    apply_k<<<1, 128, 0, stream>>>(cand, count, partial, mask, w_buf);

    softmax_k<<<BB, 1024, 0, stream>>>(w_buf, p_buf);
    scale_k<<<8192, 256, 0, stream>>>(v_buf, p_buf, out);
}